// Round 1
// baseline (13296.582 us; speedup 1.0000x reference)
//
#include <hip/hip_runtime.h>
#include <math.h>

// Problem constants
#define BB 32
#define TT 512
#define II 96
#define HH 256
#define MM 6
#define RR 16
#define KK 16
#define OUTD 64

// d_out region offsets (floats)
#define O_HSEQ  1048576
#define O_AIN   26214400
#define O_ACM   51380224
#define O_ATTN  76546048

// ws layout (floats): Weff(49152) Ut(24576) WQt(24576) WKt(24576) preinp(16777216)
#define WS_WEFF 0
#define WS_UT   49152
#define WS_WQT  73728
#define WS_WKT  98304
#define WS_PRE  122880
#define WS_NEED_FLOATS (122880 + 16777216)

// ---------------------------------------------------------------------------
// K0: build Weff[m] = W_in[m] @ W_ip[m]  (m=0..3) and pre-transpose U, W_Q, W_K
// blocks 0..191: one Weff row each; blocks 192..287: transpose rows
// ---------------------------------------------------------------------------
__global__ __launch_bounds__(256) void rim_weff(
    const float* __restrict__ Wtask, const float* __restrict__ Wsens,
    const float* __restrict__ Wip,
    const float* __restrict__ U, const float* __restrict__ WQ, const float* __restrict__ WK,
    float* __restrict__ Weff, float* __restrict__ Ut, float* __restrict__ WQt, float* __restrict__ WKt)
{
  __shared__ float row[256];
  const int bidx = blockIdx.x;
  const int tid = threadIdx.x;
  if (bidx < 192) {
    int m, i;
    if (bidx < 32)       { m = 0; i = bidx; }
    else if (bidx < 64)  { m = 1; i = bidx - 32; }
    else if (bidx < 128) { m = 2; i = bidx - 64; }
    else                 { m = 3; i = bidx - 128; }
    row[tid] = (m < 2) ? Wtask[(m * 32 + i) * 256 + tid]
                       : Wsens[((m - 2) * 64 + i) * 256 + tid];
    __syncthreads();
    float acc = 0.f;
    const float* wip = Wip + m * 65536 + tid;
    #pragma unroll 8
    for (int j = 0; j < 256; ++j) acc += row[j] * wip[j * 256];
    const int base = (m == 0) ? 0 : (m == 1) ? 8192 : (m == 2) ? 16384 : 32768;
    Weff[base + i * 256 + tid] = acc;
  } else {
    const int p = bidx - 192;       // 0..95
    const int m = p >> 4, r = p & 15;
    Ut [(m * 16 + r) * 256 + tid] = U [m * 4096 + tid * 16 + r];
    WQt[(m * 16 + r) * 256 + tid] = WQ[m * 4096 + tid * 16 + r];
    WKt[(m * 16 + r) * 256 + tid] = WK[m * 4096 + tid * 16 + r];
  }
}

// ---------------------------------------------------------------------------
// K1: parallel precompute of Ain_seq output and preinp = x @ Weff (per t,b)
// 16 (t,b) rows per block, 256 threads = one output column h each
// ---------------------------------------------------------------------------
__global__ __launch_bounds__(256) void rim_pre(
    const float* __restrict__ x,
    const float* __restrict__ Wtask, const float* __restrict__ Wsens,
    const float* __restrict__ Weff,
    float* __restrict__ Ain, float* __restrict__ preinp, int use_pre)
{
  __shared__ float xr[16][96];
  const int tid = threadIdx.x;
  const int rb0 = blockIdx.x * 16;
  for (int idx = tid; idx < 16 * 96; idx += 256) {
    int r = idx / 96, c = idx % 96;
    int rb = rb0 + r; int t = rb >> 5, b = rb & 31;
    xr[r][c] = x[(b * TT + t) * II + c];
  }
  __syncthreads();
  const int h = tid;
  float acc[16];

  // A_in for m=0..3 (m=4,5 are zeros)
  for (int m = 0; m < 4; ++m) {
    const int cnt  = (m < 2) ? 32 : 64;
    const int xoff = (m < 2) ? 64 : 0;
    const float* W = (m < 2) ? (Wtask + m * 32 * 256) : (Wsens + (m - 2) * 64 * 256);
    #pragma unroll
    for (int r = 0; r < 16; ++r) acc[r] = 0.f;
    for (int i = 0; i < cnt; ++i) {
      float w = W[i * 256 + h];
      #pragma unroll
      for (int r = 0; r < 16; ++r) acc[r] += xr[r][xoff + i] * w;
    }
    #pragma unroll
    for (int r = 0; r < 16; ++r) {
      int rb = rb0 + r; int t = rb >> 5, b = rb & 31;
      Ain[((t * 32 + b) * 6 + m) * 256 + h] = acc[r];
    }
  }
  #pragma unroll
  for (int r = 0; r < 16; ++r) {
    int rb = rb0 + r; int t = rb >> 5, b = rb & 31;
    Ain[((t * 32 + b) * 6 + 4) * 256 + h] = 0.f;
    Ain[((t * 32 + b) * 6 + 5) * 256 + h] = 0.f;
  }

  if (use_pre) {
    for (int m = 0; m < 4; ++m) {
      const int cnt  = (m < 2) ? 32 : 64;
      const int xoff = (m < 2) ? 64 : 0;
      const int base = (m == 0) ? 0 : (m == 1) ? 8192 : (m == 2) ? 16384 : 32768;
      #pragma unroll
      for (int r = 0; r < 16; ++r) acc[r] = 0.f;
      for (int i = 0; i < cnt; ++i) {
        float w = Weff[base + i * 256 + h];
        #pragma unroll
        for (int r = 0; r < 16; ++r) acc[r] += xr[r][xoff + i] * w;
      }
      #pragma unroll
      for (int r = 0; r < 16; ++r) {
        int rb = rb0 + r;
        preinp[(rb * 4 + m) * 256 + h] = acc[r];
      }
    }
  }
}

// ---------------------------------------------------------------------------
// K2: the sequential recurrence. One block per batch, 512 threads, H in LDS.
// ---------------------------------------------------------------------------
__global__ __launch_bounds__(512) void rim_loop(
    const float* __restrict__ x,
    const float* __restrict__ Vr, const float* __restrict__ WV,
    const float* __restrict__ Wout, const float* __restrict__ bout,
    const float* __restrict__ bip, const float* __restrict__ cbias,
    const float* __restrict__ Ut, const float* __restrict__ WQt, const float* __restrict__ WKt,
    const float* __restrict__ Weff, const float* __restrict__ preinp,
    float* __restrict__ out0, float* __restrict__ Hseq,
    float* __restrict__ Acm, float* __restrict__ attnO,
    int use_pre)
{
  __shared__ float Hl[6][256];      // recurrent state H_{t-1} -> H_t
  __shared__ float Hin[6][256];
  __shared__ float biasl[6][256];   // b_ip + cell_bias
  __shared__ float Vcp[2][6][256];  // Vc partial sums (two h' halves)
  __shared__ float tmpUr[6][16];
  __shared__ float Qc[6][16], Kc[6][16];
  __shared__ float attnl[36];
  __shared__ float pout[8][64];
  __shared__ float xl[96];
  __shared__ float inpl[4][256];

  const int b = blockIdx.x;
  const int tid = threadIdx.x;
  const int wid = tid >> 5, lane = tid & 31;

  for (int i = tid; i < 1536; i += 512) {
    int m = i >> 8, h = i & 255;
    biasl[m][h] = bip[i] + cbias[i];
    Hl[m][h] = 0.f;
  }
  __syncthreads();

  for (int t = 0; t < TT; ++t) {
    // ---- A0 (fallback only): inp = x @ Weff computed in-loop ----
    if (!use_pre) {
      if (tid < 96) xl[tid] = x[(b * TT + t) * II + tid];
      __syncthreads();
      for (int mh = tid; mh < 1024; mh += 512) {
        int m = mh >> 8, h = mh & 255;
        const int base = (m == 0) ? 0 : (m == 1) ? 8192 : (m == 2) ? 16384 : 32768;
        const int cnt  = (m < 2) ? 32 : 64;
        const int xoff = (m < 2) ? 64 : 0;
        float a = 0.f;
        for (int i = 0; i < cnt; ++i) a += xl[xoff + i] * Weff[base + i * 256 + h];
        inpl[m][h] = a;
      }
    }

    // ---- A1: tmpUr[m][r] = sum_h H[m,h] * U[m,h,r]  (via transposed Ut) ----
    for (int p = wid; p < 96; p += 16) {
      int m = p >> 4, r = p & 15;
      const float* up = Ut + (m * 16 + r) * 256;
      float s = 0.f;
      #pragma unroll
      for (int h = lane; h < 256; h += 32) s += Hl[m][h] * up[h];
      #pragma unroll
      for (int off = 16; off > 0; off >>= 1) s += __shfl_down(s, off, 32);
      if (lane == 0) tmpUr[m][r] = s;
    }
    __syncthreads();  // s1

    // ---- A2: H_in = tanh(preinp + rec + bias) ----
    for (int mh = tid; mh < 1536; mh += 512) {
      int m = mh >> 8, h = mh & 255;
      float rec = 0.f;
      const float* vp = Vr + m * 4096 + h;
      #pragma unroll
      for (int r = 0; r < 16; ++r) rec += tmpUr[m][r] * vp[r * 256];
      float pre = 0.f;
      if (m < 4) pre = use_pre ? preinp[((size_t)(t * 32 + b) * 4 + m) * 256 + h]
                               : inpl[m][h];
      Hin[m][h] = tanhf(pre + rec + biasl[m][h]);
    }
    __syncthreads();  // s2

    // ---- A3: Qc, Kc ----
    for (int p = wid; p < 192; p += 16) {
      int pq = p % 96;
      int m = pq >> 4, k = pq & 15;
      const float* wp = ((p < 96) ? WQt : WKt) + (m * 16 + k) * 256;
      float s = 0.f;
      #pragma unroll
      for (int h = lane; h < 256; h += 32) s += Hin[m][h] * wp[h];
      #pragma unroll
      for (int off = 16; off > 0; off >>= 1) s += __shfl_down(s, off, 32);
      if (lane == 0) { if (p < 96) Qc[m][k] = s; else Kc[m][k] = s; }
    }

    // ---- A4: Vc partials. Vc[h_out, m] = sum_h' Hin[m,h'] WV[m,h',h_out] ----
    {
      const int h_out = tid & 255, half = tid >> 8;
      for (int m = 0; m < 6; ++m) {
        const float* wv = WV + ((size_t)(m * 256 + half * 128)) * 256 + h_out;
        const float* hv = &Hin[m][half * 128];
        float s = 0.f;
        #pragma unroll 8
        for (int j = 0; j < 128; ++j) s += hv[j] * wv[(size_t)j * 256];
        Vcp[half][m][h_out] = s;
      }
    }
    __syncthreads();  // s3

    // ---- A5: attention scores + softmax over n ----
    if (tid < 36) {
      int m = tid / 6, n = tid % 6;
      float s = 0.f;
      #pragma unroll
      for (int k = 0; k < 16; ++k) s += Qc[m][k] * Kc[n][k];
      attnl[tid] = s * 0.25f;
    }
    __syncthreads();  // s4
    if (tid < 6) {
      int m = tid;
      float mx = -1e30f;
      #pragma unroll
      for (int n = 0; n < 6; ++n) mx = fmaxf(mx, attnl[m * 6 + n]);
      float e[6], sm = 0.f;
      #pragma unroll
      for (int n = 0; n < 6; ++n) { e[n] = expf(attnl[m * 6 + n] - mx); sm += e[n]; }
      float inv = 1.f / sm;
      #pragma unroll
      for (int n = 0; n < 6; ++n) attnl[m * 6 + n] = e[n] * inv;
    }
    __syncthreads();  // s5
    if (tid < 36) attnO[(size_t)(t * 32 + b) * 36 + tid] = attnl[tid];

    // ---- A6: A_comm, H_new, write Hseq/Acomm ----
    for (int mh = tid; mh < 1536; mh += 512) {
      int n = mh >> 8, h = mh & 255;
      float ac = 0.f;
      #pragma unroll
      for (int m = 0; m < 6; ++m)
        ac += attnl[m * 6 + n] * (Vcp[0][m][h] + Vcp[1][m][h]);
      float hn = Hin[n][h] + ac;
      Hl[n][h] = hn;
      size_t gi = ((size_t)(t * 32 + b) * 6 + n) * 256 + h;
      Hseq[gi] = hn;
      Acm[gi]  = ac;
    }
    __syncthreads();  // s6

    // ---- A7: out = H_new[4:6].flat @ W_out + b_out ----
    {
      const int o = tid & 63, js = tid >> 6;
      const float* hp = &Hl[4][0];  // Hl[4..5] contiguous 512 floats
      const float* wp = Wout + (size_t)(js * 64) * 64 + o;
      float s = 0.f;
      #pragma unroll 8
      for (int jj = 0; jj < 64; ++jj) s += hp[js * 64 + jj] * wp[(size_t)jj * 64];
      pout[js][o] = s;
    }
    __syncthreads();  // s7
    if (tid < 64) {
      float s = bout[tid];
      #pragma unroll
      for (int js = 0; js < 8; ++js) s += pout[js][tid];
      out0[(size_t)(b * TT + t) * 64 + tid] = s;
    }
    // next iter's first barrier (s1) orders remaining hazards
  }
}

// ---------------------------------------------------------------------------
extern "C" void kernel_launch(void* const* d_in, const int* in_sizes, int n_in,
                              void* d_out, int out_size, void* d_ws, size_t ws_size,
                              hipStream_t stream) {
  const float* x    = (const float*)d_in[0];
  const float* W_ip = (const float*)d_in[1];
  const float* b_ip = (const float*)d_in[2];
  const float* U    = (const float*)d_in[3];
  const float* Vr   = (const float*)d_in[4];
  const float* cb   = (const float*)d_in[5];
  const float* Wt   = (const float*)d_in[6];
  const float* Wsn  = (const float*)d_in[7];
  const float* WQ   = (const float*)d_in[8];
  const float* WK   = (const float*)d_in[9];
  const float* WV   = (const float*)d_in[10];
  const float* Wo   = (const float*)d_in[11];
  const float* bo   = (const float*)d_in[12];

  float* out  = (float*)d_out;
  float* Hseq = out + O_HSEQ;
  float* Ain  = out + O_AIN;
  float* Acm  = out + O_ACM;
  float* attn = out + O_ATTN;

  float* ws     = (float*)d_ws;
  float* Weff   = ws + WS_WEFF;
  float* Ut     = ws + WS_UT;
  float* WQt    = ws + WS_WQT;
  float* WKt    = ws + WS_WKT;
  float* preinp = ws + WS_PRE;

  const int use_pre = (ws_size >= (size_t)WS_NEED_FLOATS * sizeof(float)) ? 1 : 0;

  hipLaunchKernelGGL(rim_weff, dim3(288), dim3(256), 0, stream,
                     Wt, Wsn, W_ip, U, WQ, WK, Weff, Ut, WQt, WKt);
  hipLaunchKernelGGL(rim_pre, dim3(1024), dim3(256), 0, stream,
                     x, Wt, Wsn, Weff, Ain, preinp, use_pre);
  hipLaunchKernelGGL(rim_loop, dim3(32), dim3(512), 0, stream,
                     x, Vr, WV, Wo, bo, b_ip, cb, Ut, WQt, WKt, Weff, preinp,
                     out, Hseq, Acm, attn, use_pre);
}